// Round 4
// baseline (1560.268 us; speedup 1.0000x reference)
//
#include <hip/hip_runtime.h>
#include <hip/hip_bf16.h>
#include <stdint.h>

// Fused gather + (ep-eq)^2 + MLP(256->256->256->1) for MI355X (gfx950).
//
// Round 6: persistent blocks + T14 async-STAGE gather pipeline.
//   Round-5 counters: fused 343 us, MfmaUtil 16%, VALUBusy 27%, HBM 1.5/6.3
//   TB/s, 0 bank conflicts -> pure latency-bound serialization (gather ->
//   barrier -> GEMMs with nothing overlapping the gather).
//   This round: grid-stride persistent blocks; A-tile double-buffered in
//   LDS (2 x 32 KB); the NEXT tile's gather is register-staged in two
//   8-row half-windows (16 float4 = 64 VGPRs in flight) issued under the
//   current tile's GEMM1/GEMM2 windows; sqdiff+ds_write deferred to after
//   the following barrier (issue-early / write-late). 2 blocks/CU,
//   launch_bounds(256,2). s_setprio(1) around MFMA clusters (independent
//   blocks per CU -> T5 regime).
//
// Round 7: unchanged resubmission — round-6 bench lost to MI355X container
//   infra failure (second occurrence; round-0 resubmission recovered).
//   Kernel audited for hang/OOB: none possible (block-scoped barriers only,
//   clamped gather indices, LDS addressing bounded).

#define D 256
#define MT 64
#define THREADS 256
#define PERSIST_BLOCKS 512   // 256 CUs x 2 blocks/CU

typedef __attribute__((ext_vector_type(8))) short short8;
typedef __attribute__((ext_vector_type(4))) float f32x4;

// bf16 round-to-nearest-even
__device__ __forceinline__ unsigned short f2bf(float f) {
    unsigned int u = __float_as_uint(f);
    unsigned int r = (u + 0x7FFFu + ((u >> 16) & 1u)) >> 16;
    return (unsigned short)r;
}

// ---------------- weight packing ----------------
// Pack W (row-major fp32 [K=256][N=256]) into bf16 B-fragments for
// v_mfma_f32_16x16x32_bf16. Fragment (nt, ks): lane L holds
//   B[k = ks*32 + (L>>4)*8 + j][n = nt*16 + (L&15)], j = 0..7
__global__ void pack_w_kernel(const float* __restrict__ w1,
                              const float* __restrict__ w2,
                              unsigned short* __restrict__ out) {
    int tid = blockIdx.x * blockDim.x + threadIdx.x;   // 0..16383
    int mat = tid >> 13;
    const float* W = mat ? w2 : w1;
    unsigned short* o = out + mat * 65536;
    int rem  = tid & 8191;
    int nt   = rem >> 9;
    int ks   = (rem >> 6) & 7;
    int lane = rem & 63;
    int kbase = ks * 32 + (lane >> 4) * 8;
    int n     = nt * 16 + (lane & 15);
    short8 v;
#pragma unroll
    for (int j = 0; j < 8; ++j)
        v[j] = (short)f2bf(W[(kbase + j) * 256 + n]);
    *reinterpret_cast<short8*>(o + (((nt * 8) + ks) * 64 + lane) * 8) = v;
}

// ---------------- fused main kernel ----------------
__launch_bounds__(THREADS, 2)
__global__ void fused_kernel(const int* __restrict__ pv,
                             const int* __restrict__ qv,
                             const float* __restrict__ embf,
                             const float* __restrict__ b1,
                             const float* __restrict__ b2,
                             const float* __restrict__ w3,
                             const float* __restrict__ b3,
                             const unsigned short* __restrict__ wpack,
                             float* __restrict__ out,
                             int M) {
    // Double-buffered A tile (each reused as H tile). Row stride 512 B,
    // XOR-swizzled 16 B units (phys = u ^ (row & 31)) -> conflict-free
    // ds_read_b128 / writes.
    __shared__ unsigned char lds_a[2][MT * 512];
    __shared__ float lds_part[4][MT];

    const int tid  = threadIdx.x;
    const int lane = tid & 63;
    const int wave = tid >> 6;              // 0..3
    const int ntiles = (M + MT - 1) / MT;

    int t = blockIdx.x;
    if (t >= ntiles) return;

    const int wn    = wave;         // n quarter: cols 64*wn .. +64
    const int nbase = wn * 64;
    const int l15   = lane & 15;
    const int quad  = lane >> 4;

    const short8* wp1 = reinterpret_cast<const short8*>(wpack);
    const short8* wp2 = reinterpret_cast<const short8*>(wpack + 65536);

    // register gather window: 8 rows (p + q) = 16 float4 = 64 VGPRs
    float4 pf[8], qf[8];

    // Issue the global gather loads for half h_ (8 rows) of the tile whose
    // base row is tb_. Row indices are wave-uniform -> scalar index loads.
#define ISSUE(tb_, h_)                                                       \
    _Pragma("unroll")                                                        \
    for (int rr = 0; rr < 8; ++rr) {                                         \
        int r  = wave * 16 + (h_) * 8 + rr;                                  \
        int gi = (tb_) + r;                                                  \
        int pi = 0, qi = 0;                                                  \
        if (gi < M) { pi = pv[gi]; qi = qv[gi]; }                            \
        pf[rr] = reinterpret_cast<const float4*>(embf + (size_t)pi * D)[lane]; \
        qf[rr] = reinterpret_cast<const float4*>(embf + (size_t)qi * D)[lane]; \
    }

    // Consume the window: fp32 sqdiff, round once to bf16, swizzled ds_write.
#define PROCESS(h_, buf_)                                                    \
    _Pragma("unroll")                                                        \
    for (int rr = 0; rr < 8; ++rr) {                                         \
        int r = wave * 16 + (h_) * 8 + rr;                                   \
        float4 a = pf[rr], b = qf[rr];                                       \
        float d0 = a.x - b.x, d1 = a.y - b.y;                                \
        float d2 = a.z - b.z, d3 = a.w - b.w;                                \
        unsigned int lo = (unsigned int)f2bf(d0 * d0) |                      \
                          ((unsigned int)f2bf(d1 * d1) << 16);               \
        unsigned int hi = (unsigned int)f2bf(d2 * d2) |                      \
                          ((unsigned int)f2bf(d3 * d3) << 16);               \
        unsigned int unit = (unsigned int)(lane >> 1) ^ (unsigned int)(r & 31);\
        unsigned int addr = (unsigned int)r * 512u + (unit << 4) +           \
                            (unsigned int)(lane & 1) * 8u;                   \
        *reinterpret_cast<uint2*>(&(buf_)[addr]) = make_uint2(lo, hi);       \
    }

#define LOADB(buf, wp, ksv)                                            \
    _Pragma("unroll")                                                  \
    for (int ct = 0; ct < 4; ++ct)                                     \
        buf[ct] = (wp)[((((nbase >> 4) + ct) * 8) + (ksv)) * 64 + lane];

#define LOADA(af, ab_, ksv)                                                          \
    _Pragma("unroll")                                                                \
    for (int mt = 0; mt < 4; ++mt) {                                                 \
        int r = mt * 16 + l15;                                                       \
        unsigned int unit = (unsigned int)((ksv) * 4 + quad) ^ (unsigned int)(r & 31);\
        af[mt] = *reinterpret_cast<const short8*>(                                   \
            &(ab_)[(unsigned int)r * 512u + (unit << 4)]);                           \
    }

#define MFMA16(bu)                                                      \
    _Pragma("unroll")                                                   \
    for (int mt = 0; mt < 4; ++mt)                                      \
        _Pragma("unroll")                                               \
        for (int ct = 0; ct < 4; ++ct)                                  \
            acc[mt][ct] = __builtin_amdgcn_mfma_f32_16x16x32_bf16(      \
                af[mt], bu[ct], acc[mt][ct], 0, 0, 0);

    f32x4 acc[4][4];
    short8 bb0[4], bb1[4];

    // ---- prologue: gather tile t into buffer 0 (sequential halves) ----
    {
        unsigned char* nb = lds_a[0];
        ISSUE(t * MT, 0)
        PROCESS(0, nb)
        ISSUE(t * MT, 1)
        PROCESS(1, nb)
    }
    __syncthreads();

    int cur = 0;
    for (; t < ntiles; t += gridDim.x) {
        const int tb   = t * MT;
        const int tnb  = (t + (int)gridDim.x) * MT;   // next tile base
        const bool pre = (t + (int)gridDim.x) < ntiles;
        unsigned char* ab = lds_a[cur];
        unsigned char* nb = lds_a[cur ^ 1];

        // issue next tile's first gather half under GEMM1
        if (pre) ISSUE(tnb, 0)

        // ================= GEMM1: h1 = relu(A @ W1 + b1) =================
#pragma unroll
        for (int mt = 0; mt < 4; ++mt)
#pragma unroll
            for (int ct = 0; ct < 4; ++ct)
                acc[mt][ct] = (f32x4){0.f, 0.f, 0.f, 0.f};

        LOADB(bb0, wp1, 0)
        LOADB(bb1, wp1, 1)
#pragma unroll
        for (int ks = 0; ks < 8; ++ks) {
            short8 af[4];
            LOADA(af, ab, ks)
            __builtin_amdgcn_s_setprio(1);
            if (ks & 1) {
                MFMA16(bb1)
                __builtin_amdgcn_s_setprio(0);
                if (ks + 2 < 8) LOADB(bb1, wp1, ks + 2)
            } else {
                MFMA16(bb0)
                __builtin_amdgcn_s_setprio(0);
                if (ks + 2 < 8) LOADB(bb0, wp1, ks + 2)
            }
        }

        // A is dead; all waves must finish reading it before H overwrites it.
        __syncthreads();

        // epilogue 1: +b1, relu, bf16 -> ab (as H). C/D: col=lane&15, row=quad*4+j
#pragma unroll
        for (int ct = 0; ct < 4; ++ct) {
            int c = nbase + ct * 16 + l15;
            float bias = b1[c];
#pragma unroll
            for (int mt = 0; mt < 4; ++mt) {
#pragma unroll
                for (int j = 0; j < 4; ++j) {
                    float v = acc[mt][ct][j] + bias;
                    v = fmaxf(v, 0.f);
                    int r = mt * 16 + quad * 4 + j;
                    unsigned int unit = (unsigned int)(c >> 3) ^ (unsigned int)(r & 31);
                    unsigned int addr = (unsigned int)r * 512u + (unit << 4) + (unsigned int)(c & 7) * 2u;
                    *reinterpret_cast<unsigned short*>(&ab[addr]) = f2bf(v);
                }
            }
        }

        // write-late: consume gather half0 into the other buffer, then
        // issue half1 under GEMM2
        if (pre) {
            PROCESS(0, nb)
            ISSUE(tnb, 1)
        }
        __syncthreads();

        // ================= GEMM2: relu(H @ W2 + b2), fused w3 dot =================
#pragma unroll
        for (int mt = 0; mt < 4; ++mt)
#pragma unroll
            for (int ct = 0; ct < 4; ++ct)
                acc[mt][ct] = (f32x4){0.f, 0.f, 0.f, 0.f};

        LOADB(bb0, wp2, 0)
        LOADB(bb1, wp2, 1)
#pragma unroll
        for (int ks = 0; ks < 8; ++ks) {
            short8 af[4];
            LOADA(af, ab, ks)
            __builtin_amdgcn_s_setprio(1);
            if (ks & 1) {
                MFMA16(bb1)
                __builtin_amdgcn_s_setprio(0);
                if (ks + 2 < 8) LOADB(bb1, wp2, ks + 2)
            } else {
                MFMA16(bb0)
                __builtin_amdgcn_s_setprio(0);
                if (ks + 2 < 8) LOADB(bb0, wp2, ks + 2)
            }
        }

        float part[4][4];
#pragma unroll
        for (int mt = 0; mt < 4; ++mt)
#pragma unroll
            for (int j = 0; j < 4; ++j)
                part[mt][j] = 0.f;

#pragma unroll
        for (int ct = 0; ct < 4; ++ct) {
            int c = nbase + ct * 16 + l15;
            float bias = b2[c];
            float w3v  = w3[c];
#pragma unroll
            for (int mt = 0; mt < 4; ++mt)
#pragma unroll
                for (int j = 0; j < 4; ++j) {
                    float v = acc[mt][ct][j] + bias;
                    v = fmaxf(v, 0.f);
                    part[mt][j] += v * w3v;
                }
        }

        // reduce across the 16 lanes of each quad (same rows, different cols)
#pragma unroll
        for (int msk = 8; msk >= 1; msk >>= 1)
#pragma unroll
            for (int mt = 0; mt < 4; ++mt)
#pragma unroll
                for (int j = 0; j < 4; ++j)
                    part[mt][j] += __shfl_xor(part[mt][j], msk, 64);

        if (l15 == 0) {
#pragma unroll
            for (int mt = 0; mt < 4; ++mt)
#pragma unroll
                for (int j = 0; j < 4; ++j) {
                    int r = mt * 16 + quad * 4 + j;
                    lds_part[wn][r] = part[mt][j];
                }
        }
        __syncthreads();

        if (tid < MT) {
            int gi = tb + tid;
            if (gi < M) {
                float s = lds_part[0][tid] + lds_part[1][tid] +
                          lds_part[2][tid] + lds_part[3][tid] + b3[0];
                out[gi] = s;
            }
        }

        // write-late: consume gather half1 into the other buffer
        if (pre) PROCESS(1, nb)
        __syncthreads();
        cur ^= 1;
    }
}

extern "C" void kernel_launch(void* const* d_in, const int* in_sizes, int n_in,
                              void* d_out, int out_size, void* d_ws, size_t ws_size,
                              hipStream_t stream) {
    const int*   pv  = (const int*)d_in[0];
    const int*   qv  = (const int*)d_in[1];
    const float* emb = (const float*)d_in[2];
    const float* w1  = (const float*)d_in[3];
    const float* b1  = (const float*)d_in[4];
    const float* w2  = (const float*)d_in[5];
    const float* b2  = (const float*)d_in[6];
    const float* w3  = (const float*)d_in[7];
    const float* b3  = (const float*)d_in[8];
    float* out = (float*)d_out;
    const int M  = in_sizes[0];

    // Workspace: only the 256 KB packed-weight buffer.
    unsigned short* wpack = (unsigned short*)d_ws;

    pack_w_kernel<<<32, 512, 0, stream>>>(w1, w2, wpack);

    int ntiles = (M + MT - 1) / MT;
    int nblk = ntiles < PERSIST_BLOCKS ? ntiles : PERSIST_BLOCKS;
    fused_kernel<<<nblk, THREADS, 0, stream>>>(
        pv, qv, emb, b1, b2, w3, b3, wpack, out, M);
}

// Round 5
// 1389.939 us; speedup vs baseline: 1.1225x; 1.1225x over previous
//
#include <hip/hip_runtime.h>
#include <hip/hip_bf16.h>
#include <stdint.h>

// Fused gather + (ep-eq)^2 + MLP(256->256->256->1) for MI355X (gfx950).
//
// Round 8: skinny pipelined gather (fix round-6's scratch spill).
//   Round-6 counters: WRITE_SIZE 2 MB -> 665 MB, FETCH 0.5 -> 2.0 GB,
//   fused 1384 us: the 64-VGPR register gather window (pf[8]/qf[8]) held
//   live across barriers spilled to scratch once per tile -> kernel became
//   scratch-BW-bound. Mechanism (hide gather under MFMA) stands; window
//   was too fat.
//   This round: stage 1 row per K-step with a depth-3 rotating window
//   (3 x 8 = 24 VGPRs), spread across GEMM1 (rows 0-7) and GEMM2 (rows
//   8-15); only 2 sets live across the epilogue barrier. Tile indices
//   prefetched a full tile ahead (2 regs/lane, __shfl-distributed with
//   compile-time lane) -> no index->row dependent chain in steady state.
//   All rotation indices compile-time (fully unrolled; rule #20).
//   2 blocks/CU (LDS 66.5 KB), launch_bounds(256,2).

#define D 256
#define MT 64
#define THREADS 256
#define PERSIST_BLOCKS 512   // 256 CUs x 2 blocks/CU

typedef __attribute__((ext_vector_type(8))) short short8;
typedef __attribute__((ext_vector_type(4))) float f32x4;

// bf16 round-to-nearest-even
__device__ __forceinline__ unsigned short f2bf(float f) {
    unsigned int u = __float_as_uint(f);
    unsigned int r = (u + 0x7FFFu + ((u >> 16) & 1u)) >> 16;
    return (unsigned short)r;
}

// ---------------- weight packing ----------------
// Pack W (row-major fp32 [K=256][N=256]) into bf16 B-fragments for
// v_mfma_f32_16x16x32_bf16. Fragment (nt, ks): lane L holds
//   B[k = ks*32 + (L>>4)*8 + j][n = nt*16 + (L&15)], j = 0..7
__global__ void pack_w_kernel(const float* __restrict__ w1,
                              const float* __restrict__ w2,
                              unsigned short* __restrict__ out) {
    int tid = blockIdx.x * blockDim.x + threadIdx.x;   // 0..16383
    int mat = tid >> 13;
    const float* W = mat ? w2 : w1;
    unsigned short* o = out + mat * 65536;
    int rem  = tid & 8191;
    int nt   = rem >> 9;
    int ks   = (rem >> 6) & 7;
    int lane = rem & 63;
    int kbase = ks * 32 + (lane >> 4) * 8;
    int n     = nt * 16 + (lane & 15);
    short8 v;
#pragma unroll
    for (int j = 0; j < 8; ++j)
        v[j] = (short)f2bf(W[(kbase + j) * 256 + n]);
    *reinterpret_cast<short8*>(o + (((nt * 8) + ks) * 64 + lane) * 8) = v;
}

// ---------------- fused main kernel ----------------
__launch_bounds__(THREADS, 2)
__global__ void fused_kernel(const int* __restrict__ pv,
                             const int* __restrict__ qv,
                             const float* __restrict__ embf,
                             const float* __restrict__ b1,
                             const float* __restrict__ b2,
                             const float* __restrict__ w3,
                             const float* __restrict__ b3,
                             const unsigned short* __restrict__ wpack,
                             float* __restrict__ out,
                             int M) {
    // Double-buffered A tile (each reused as H tile). Row stride 512 B,
    // XOR-swizzled 16 B units (phys = u ^ (row & 31)) -> conflict-free
    // ds_read_b128 / writes.
    __shared__ unsigned char lds_a[2][MT * 512];
    __shared__ float lds_part[4][MT];

    const int tid  = threadIdx.x;
    const int lane = tid & 63;
    const int wave = tid >> 6;              // 0..3
    const int ntiles = (M + MT - 1) / MT;

    int t = blockIdx.x;
    if (t >= ntiles) return;

    const int wn    = wave;         // n quarter: cols 64*wn .. +64
    const int nbase = wn * 64;
    const int l15   = lane & 15;
    const int quad  = lane >> 4;

    const short8* wp1 = reinterpret_cast<const short8*>(wpack);
    const short8* wp2 = reinterpret_cast<const short8*>(wpack + 65536);

    // depth-3 rotating gather window: 3 x (float4 p + float4 q) = 24 VGPRs
    float4 sp[3], sq[3];
    // per-wave tile indices: lane (L&15) holds the index for local row L&15
    int ipn, iqn;   // tile currently being staged (ready)
    int ipf, iqf;   // in flight for the tile after that

    // Load the per-wave index vector for tile base tb_ (clamped).
#define LOADIDX(ip_, iq_, tb_)                                           \
    {                                                                    \
        int gi_ = (tb_) + wave * 16 + l15;                               \
        gi_ = gi_ < M ? gi_ : M - 1;                                     \
        ip_ = pv[gi_]; iq_ = qv[gi_];                                    \
    }

    // Issue global gather loads for local row s_ (0..15) of the staged tile.
#define ISSUE_ROW(slot_, s_)                                                     \
    {                                                                            \
        int pi_ = __shfl(ipn, (s_), 64);                                         \
        int qi_ = __shfl(iqn, (s_), 64);                                         \
        sp[slot_] = reinterpret_cast<const float4*>(embf + (size_t)pi_ * D)[lane]; \
        sq[slot_] = reinterpret_cast<const float4*>(embf + (size_t)qi_ * D)[lane]; \
    }

    // Consume window slot: fp32 sqdiff -> bf16 -> swizzled ds_write (8 B/lane).
#define PROC_ROW(slot_, s_, buf_)                                                \
    {                                                                            \
        int r_ = wave * 16 + (s_);                                               \
        float4 a_ = sp[slot_], b_ = sq[slot_];                                   \
        float d0 = a_.x - b_.x, d1 = a_.y - b_.y;                                \
        float d2 = a_.z - b_.z, d3 = a_.w - b_.w;                                \
        unsigned int lo = (unsigned int)f2bf(d0 * d0) |                          \
                          ((unsigned int)f2bf(d1 * d1) << 16);                   \
        unsigned int hi = (unsigned int)f2bf(d2 * d2) |                          \
                          ((unsigned int)f2bf(d3 * d3) << 16);                   \
        unsigned int unit_ = (unsigned int)(lane >> 1) ^ (unsigned int)(r_ & 31);\
        unsigned int addr_ = (unsigned int)r_ * 512u + (unit_ << 4) +            \
                             (unsigned int)(lane & 1) * 8u;                      \
        *reinterpret_cast<uint2*>(&(buf_)[addr_]) = make_uint2(lo, hi);          \
    }

#define LOADB(buf, wp, ksv)                                            \
    _Pragma("unroll")                                                  \
    for (int ct = 0; ct < 4; ++ct)                                     \
        buf[ct] = (wp)[((((nbase >> 4) + ct) * 8) + (ksv)) * 64 + lane];

#define LOADA(af, ab_, ksv)                                                          \
    _Pragma("unroll")                                                                \
    for (int mt = 0; mt < 4; ++mt) {                                                 \
        int r = mt * 16 + l15;                                                       \
        unsigned int unit = (unsigned int)((ksv) * 4 + quad) ^ (unsigned int)(r & 31);\
        af[mt] = *reinterpret_cast<const short8*>(                                   \
            &(ab_)[(unsigned int)r * 512u + (unit << 4)]);                           \
    }

#define MFMA16(bu)                                                      \
    _Pragma("unroll")                                                   \
    for (int mt = 0; mt < 4; ++mt)                                      \
        _Pragma("unroll")                                               \
        for (int ct = 0; ct < 4; ++ct)                                  \
            acc[mt][ct] = __builtin_amdgcn_mfma_f32_16x16x32_bf16(      \
                af[mt], bu[ct], acc[mt][ct], 0, 0, 0);

    f32x4 acc[4][4];
    short8 bb0[4], bb1[4];

    // ---- prologue: stage tile t into buffer 0; prefetch next indices ----
    LOADIDX(ipn, iqn, t * MT)
    LOADIDX(ipf, iqf, (t + (int)gridDim.x) * MT)
    {
        unsigned char* b0 = lds_a[0];
        ISSUE_ROW(0, 0)
        ISSUE_ROW(1, 1)
#pragma unroll
        for (int s = 0; s < 16; ++s) {
            if (s + 2 < 16) ISSUE_ROW((s + 2) % 3, s + 2)
            PROC_ROW(s % 3, s, b0)
        }
    }
    __syncthreads();

    int cur = 0;
    for (; t < ntiles; t += gridDim.x) {
        const int tb   = t * MT;
        const bool pre = (t + (int)gridDim.x) < ntiles;
        unsigned char* ab = lds_a[cur];
        unsigned char* nb = lds_a[cur ^ 1];

        // rotate index sets; issue index load two tiles ahead
        ipn = ipf; iqn = iqf;
        LOADIDX(ipf, iqf, (t + 2 * (int)gridDim.x) * MT)

        // ================= GEMM1: h1 = relu(A @ W1 + b1) =================
#pragma unroll
        for (int mt = 0; mt < 4; ++mt)
#pragma unroll
            for (int ct = 0; ct < 4; ++ct)
                acc[mt][ct] = (f32x4){0.f, 0.f, 0.f, 0.f};

        LOADB(bb0, wp1, 0)
        LOADB(bb1, wp1, 1)
        if (pre) {
            ISSUE_ROW(0, 0)
            ISSUE_ROW(1, 1)
        }
#pragma unroll
        for (int ks = 0; ks < 8; ++ks) {      // staged rows s = ks (0..7)
            short8 af[4];
            LOADA(af, ab, ks)
            if (pre) ISSUE_ROW((ks + 2) % 3, ks + 2)
            __builtin_amdgcn_s_setprio(1);
            if (ks & 1) { MFMA16(bb1) } else { MFMA16(bb0) }
            __builtin_amdgcn_s_setprio(0);
            if (ks & 1) {
                if (ks + 2 < 8) LOADB(bb1, wp1, ks + 2)
            } else {
                if (ks + 2 < 8) LOADB(bb0, wp1, ks + 2)
            }
            if (pre) PROC_ROW(ks % 3, ks, nb)
        }

        // A is dead; all waves must finish reading it before H overwrites it.
        __syncthreads();

        // epilogue 1: +b1, relu, bf16 -> ab (as H). C/D: col=lane&15, row=quad*4+j
#pragma unroll
        for (int ct = 0; ct < 4; ++ct) {
            int c = nbase + ct * 16 + l15;
            float bias = b1[c];
#pragma unroll
            for (int mt = 0; mt < 4; ++mt) {
#pragma unroll
                for (int j = 0; j < 4; ++j) {
                    float v = acc[mt][ct][j] + bias;
                    v = fmaxf(v, 0.f);
                    int r = mt * 16 + quad * 4 + j;
                    unsigned int unit = (unsigned int)(c >> 3) ^ (unsigned int)(r & 31);
                    unsigned int addr = (unsigned int)r * 512u + (unit << 4) + (unsigned int)(c & 7) * 2u;
                    *reinterpret_cast<unsigned short*>(&ab[addr]) = f2bf(v);
                }
            }
        }
        __syncthreads();

        // ================= GEMM2: relu(H @ W2 + b2), fused w3 dot =================
#pragma unroll
        for (int mt = 0; mt < 4; ++mt)
#pragma unroll
            for (int ct = 0; ct < 4; ++ct)
                acc[mt][ct] = (f32x4){0.f, 0.f, 0.f, 0.f};

        LOADB(bb0, wp2, 0)
        LOADB(bb1, wp2, 1)
#pragma unroll
        for (int ks = 0; ks < 8; ++ks) {      // staged rows s = ks + 8 (8..15)
            short8 af[4];
            LOADA(af, ab, ks)
            if (pre && (ks + 10) < 16) ISSUE_ROW((ks + 10) % 3, ks + 10)
            __builtin_amdgcn_s_setprio(1);
            if (ks & 1) { MFMA16(bb1) } else { MFMA16(bb0) }
            __builtin_amdgcn_s_setprio(0);
            if (ks & 1) {
                if (ks + 2 < 8) LOADB(bb1, wp2, ks + 2)
            } else {
                if (ks + 2 < 8) LOADB(bb0, wp2, ks + 2)
            }
            if (pre) PROC_ROW((ks + 8) % 3, ks + 8, nb)
        }

        float part[4][4];
#pragma unroll
        for (int mt = 0; mt < 4; ++mt)
#pragma unroll
            for (int j = 0; j < 4; ++j)
                part[mt][j] = 0.f;

#pragma unroll
        for (int ct = 0; ct < 4; ++ct) {
            int c = nbase + ct * 16 + l15;
            float bias = b2[c];
            float w3v  = w3[c];
#pragma unroll
            for (int mt = 0; mt < 4; ++mt)
#pragma unroll
                for (int j = 0; j < 4; ++j) {
                    float v = acc[mt][ct][j] + bias;
                    v = fmaxf(v, 0.f);
                    part[mt][j] += v * w3v;
                }
        }

        // reduce across the 16 lanes of each quad (same rows, different cols)
#pragma unroll
        for (int msk = 8; msk >= 1; msk >>= 1)
#pragma unroll
            for (int mt = 0; mt < 4; ++mt)
#pragma unroll
                for (int j = 0; j < 4; ++j)
                    part[mt][j] += __shfl_xor(part[mt][j], msk, 64);

        if (l15 == 0) {
#pragma unroll
            for (int mt = 0; mt < 4; ++mt)
#pragma unroll
                for (int j = 0; j < 4; ++j) {
                    int r = mt * 16 + quad * 4 + j;
                    lds_part[wn][r] = part[mt][j];
                }
        }
        __syncthreads();   // also separates last H-read / staged-A writes
                           // from the next iteration's buffer reuse

        if (tid < MT) {
            int gi = tb + tid;
            if (gi < M) {
                float s = lds_part[0][tid] + lds_part[1][tid] +
                          lds_part[2][tid] + lds_part[3][tid] + b3[0];
                out[gi] = s;
            }
        }
        cur ^= 1;
    }
}

extern "C" void kernel_launch(void* const* d_in, const int* in_sizes, int n_in,
                              void* d_out, int out_size, void* d_ws, size_t ws_size,
                              hipStream_t stream) {
    const int*   pv  = (const int*)d_in[0];
    const int*   qv  = (const int*)d_in[1];
    const float* emb = (const float*)d_in[2];
    const float* w1  = (const float*)d_in[3];
    const float* b1  = (const float*)d_in[4];
    const float* w2  = (const float*)d_in[5];
    const float* b2  = (const float*)d_in[6];
    const float* w3  = (const float*)d_in[7];
    const float* b3  = (const float*)d_in[8];
    float* out = (float*)d_out;
    const int M  = in_sizes[0];

    // Workspace: only the 256 KB packed-weight buffer.
    unsigned short* wpack = (unsigned short*)d_ws;

    pack_w_kernel<<<32, 512, 0, stream>>>(w1, w2, wpack);

    int ntiles = (M + MT - 1) / MT;
    int nblk = ntiles < PERSIST_BLOCKS ? ntiles : PERSIST_BLOCKS;
    fused_kernel<<<nblk, THREADS, 0, stream>>>(
        pv, qv, emb, b1, b2, w3, b3, wpack, out, M);
}

// Round 6
// 530.145 us; speedup vs baseline: 2.9431x; 2.6218x over previous
//
#include <hip/hip_runtime.h>
#include <hip/hip_bf16.h>
#include <stdint.h>

// Fused gather + (ep-eq)^2 + MLP(256->256->256->1) for MI355X (gfx950).
//
// Round 9: TLP instead of register pipelining.
//   Rounds 6/8 proved any cross-barrier register gather window spills:
//   unified VGPR+AGPR pool is 512/SIMD (waves halve at 64/128/256), and
//   acc(64)+bb(32)+window does not fit at >2 waves/SIMD. The spill's
//   ~190 MB scratch traffic also evicted the L3-resident embedding table
//   (FETCH 0.5 -> 1.9 GB). Abandon ILP pipelining; hide gather latency
//   with wave count:
//   - bf16 embedding table restored (halves gather bytes, L3-friendly).
//   - 512-thread blocks, 8 waves, wave tile 32x64 -> acc[2][4]=32 regs,
//     total ~105 unified regs <= 128.
//   - __launch_bounds__(512,4) -> 128-reg cap -> 2 blocks/CU = 16
//     waves/CU (was 12 at round 1's 234 us).
//   - One tile per block, grid = ntiles; cross-block TLP hides gather.
//   - Depth-2 B-fragment register pipeline kept (keeps K-loop off the
//     L2 latency path); s_setprio(1) around MFMA clusters.

#define D 256
#define MT 64
#define THREADS 512

typedef __attribute__((ext_vector_type(8))) short short8;
typedef __attribute__((ext_vector_type(4))) float f32x4;

// bf16 round-to-nearest-even
__device__ __forceinline__ unsigned short f2bf(float f) {
    unsigned int u = __float_as_uint(f);
    unsigned int r = (u + 0x7FFFu + ((u >> 16) & 1u)) >> 16;
    return (unsigned short)r;
}
__device__ __forceinline__ float bflo(unsigned int u) { return __uint_as_float(u << 16); }
__device__ __forceinline__ float bfhi(unsigned int u) { return __uint_as_float(u & 0xFFFF0000u); }

__device__ __forceinline__ unsigned int sqdiff2(unsigned int p, unsigned int q) {
    float d0 = bflo(p) - bflo(q);
    float d1 = bfhi(p) - bfhi(q);
    return (unsigned int)f2bf(d0 * d0) | ((unsigned int)f2bf(d1 * d1) << 16);
}

// ---------------- embedding fp32 -> bf16 table ----------------
__global__ void conv_emb_kernel(const float* __restrict__ in,
                                unsigned short* __restrict__ out, int nchunks) {
    int i = blockIdx.x * blockDim.x + threadIdx.x;
    if (i >= nchunks) return;
    const float4* p = reinterpret_cast<const float4*>(in) + 2 * (size_t)i;
    float4 a = p[0], b = p[1];
    uint4 o;
    o.x = (unsigned int)f2bf(a.x) | ((unsigned int)f2bf(a.y) << 16);
    o.y = (unsigned int)f2bf(a.z) | ((unsigned int)f2bf(a.w) << 16);
    o.z = (unsigned int)f2bf(b.x) | ((unsigned int)f2bf(b.y) << 16);
    o.w = (unsigned int)f2bf(b.z) | ((unsigned int)f2bf(b.w) << 16);
    reinterpret_cast<uint4*>(out)[i] = o;
}

// ---------------- weight packing ----------------
// Pack W (row-major fp32 [K=256][N=256]) into bf16 B-fragments for
// v_mfma_f32_16x16x32_bf16. Fragment (nt, ks): lane L holds
//   B[k = ks*32 + (L>>4)*8 + j][n = nt*16 + (L&15)], j = 0..7
__global__ void pack_w_kernel(const float* __restrict__ w1,
                              const float* __restrict__ w2,
                              unsigned short* __restrict__ out) {
    int tid = blockIdx.x * blockDim.x + threadIdx.x;   // 0..16383
    int mat = tid >> 13;
    const float* W = mat ? w2 : w1;
    unsigned short* o = out + mat * 65536;
    int rem  = tid & 8191;
    int nt   = rem >> 9;
    int ks   = (rem >> 6) & 7;
    int lane = rem & 63;
    int kbase = ks * 32 + (lane >> 4) * 8;
    int n     = nt * 16 + (lane & 15);
    short8 v;
#pragma unroll
    for (int j = 0; j < 8; ++j)
        v[j] = (short)f2bf(W[(kbase + j) * 256 + n]);
    *reinterpret_cast<short8*>(o + (((nt * 8) + ks) * 64 + lane) * 8) = v;
}

// ---------------- fused main kernel ----------------
template <bool BF16T>
__launch_bounds__(THREADS, 4)
__global__ void fused_kernel(const int* __restrict__ pv,
                             const int* __restrict__ qv,
                             const float* __restrict__ embf,
                             const unsigned short* __restrict__ embb,
                             const float* __restrict__ b1,
                             const float* __restrict__ b2,
                             const float* __restrict__ w3,
                             const float* __restrict__ b3,
                             const unsigned short* __restrict__ wpack,
                             float* __restrict__ out,
                             int M) {
    // A tile (reused as H tile). Row stride 512 B, XOR-swizzled 16 B units
    // (phys = u ^ (row & 31)) -> conflict-free ds_read_b128 / writes.
    __shared__ unsigned char lds_a[MT * 512];
    __shared__ float lds_part[4][MT];

    const int tid  = threadIdx.x;
    const int lane = tid & 63;
    const int wave = tid >> 6;              // 0..7
    const int base = blockIdx.x * MT;

    // ---- phase 0: gather + squared diff -> bf16 -> lds_a ----
    if (BF16T) {
        // 2 rows per iteration: lanes 0-31 row r, lanes 32-63 row r+1.
#pragma unroll
        for (int it = 0; it < 4; ++it) {
            int r  = wave * 8 + it * 2 + (lane >> 5);
            int gi = base + r;
            int pi = 0, qi = 0;
            if (gi < M) { pi = pv[gi]; qi = qv[gi]; }
            int c = lane & 31;                                  // 16 B unit in row
            uint4 a = *(reinterpret_cast<const uint4*>(embb + (size_t)pi * D) + c);
            uint4 b = *(reinterpret_cast<const uint4*>(embb + (size_t)qi * D) + c);
            uint4 o;
            o.x = sqdiff2(a.x, b.x);
            o.y = sqdiff2(a.y, b.y);
            o.z = sqdiff2(a.z, b.z);
            o.w = sqdiff2(a.w, b.w);
            unsigned int unit = (unsigned int)c ^ (unsigned int)(r & 31);
            *reinterpret_cast<uint4*>(&lds_a[(unsigned int)r * 512u + (unit << 4)]) = o;
        }
    } else {
        // fp32 fallback: 1 row per wave-iteration, 16 B/lane.
#pragma unroll
        for (int rr = 0; rr < 8; ++rr) {
            int r  = wave * 8 + rr;
            int gi = base + r;
            int pi = 0, qi = 0;
            if (gi < M) { pi = pv[gi]; qi = qv[gi]; }
            const float4* ep = reinterpret_cast<const float4*>(embf + (size_t)pi * D);
            const float4* eq = reinterpret_cast<const float4*>(embf + (size_t)qi * D);
            float4 a = ep[lane];
            float4 b = eq[lane];
            float d0 = a.x - b.x, d1 = a.y - b.y, d2 = a.z - b.z, d3 = a.w - b.w;
            unsigned int lo = (unsigned int)f2bf(d0 * d0) | ((unsigned int)f2bf(d1 * d1) << 16);
            unsigned int hi = (unsigned int)f2bf(d2 * d2) | ((unsigned int)f2bf(d3 * d3) << 16);
            unsigned int unit = (unsigned int)(lane >> 1) ^ (unsigned int)(r & 31);
            unsigned int addr = (unsigned int)r * 512u + (unit << 4) + (unsigned int)(lane & 1) * 8u;
            *reinterpret_cast<uint2*>(&lds_a[addr]) = make_uint2(lo, hi);
        }
    }
    __syncthreads();

    const int mhalf = wave >> 2;    // row half: rows 32*mhalf .. +32
    const int nq    = wave & 3;     // n quarter: cols 64*nq .. +64
    const int nbase = nq * 64;
    const int rbase = mhalf * 32;
    const int l15   = lane & 15;
    const int quad  = lane >> 4;

    const short8* wp1 = reinterpret_cast<const short8*>(wpack);
    const short8* wp2 = reinterpret_cast<const short8*>(wpack + 65536);

    f32x4 acc[2][4];
    // depth-2 rotating B-fragment pipeline (32 VGPRs)
    short8 bb0[4], bb1[4];

#define LOADB(buf, wp, ksv)                                            \
    _Pragma("unroll")                                                  \
    for (int ct = 0; ct < 4; ++ct)                                     \
        buf[ct] = (wp)[((((nbase >> 4) + ct) * 8) + (ksv)) * 64 + lane];

#define LOADA(af, ksv)                                                               \
    _Pragma("unroll")                                                                \
    for (int mt = 0; mt < 2; ++mt) {                                                 \
        int r = rbase + mt * 16 + l15;                                               \
        unsigned int unit = (unsigned int)((ksv) * 4 + quad) ^ (unsigned int)(r & 31);\
        af[mt] = *reinterpret_cast<const short8*>(                                   \
            &lds_a[(unsigned int)r * 512u + (unit << 4)]);                           \
    }

#define MFMA8(bu)                                                       \
    _Pragma("unroll")                                                   \
    for (int mt = 0; mt < 2; ++mt)                                      \
        _Pragma("unroll")                                               \
        for (int ct = 0; ct < 4; ++ct)                                  \
            acc[mt][ct] = __builtin_amdgcn_mfma_f32_16x16x32_bf16(      \
                af[mt], bu[ct], acc[mt][ct], 0, 0, 0);

    // ================= GEMM1: h1 = relu(A @ W1 + b1) =================
#pragma unroll
    for (int mt = 0; mt < 2; ++mt)
#pragma unroll
        for (int ct = 0; ct < 4; ++ct)
            acc[mt][ct] = (f32x4){0.f, 0.f, 0.f, 0.f};

    LOADB(bb0, wp1, 0)
    LOADB(bb1, wp1, 1)
#pragma unroll
    for (int ks = 0; ks < 8; ++ks) {
        short8 af[2];
        LOADA(af, ks)
        __builtin_amdgcn_s_setprio(1);
        if (ks & 1) { MFMA8(bb1) } else { MFMA8(bb0) }
        __builtin_amdgcn_s_setprio(0);
        if (ks & 1) {
            if (ks + 2 < 8) LOADB(bb1, wp1, ks + 2)
        } else {
            if (ks + 2 < 8) LOADB(bb0, wp1, ks + 2)
        }
    }

    // A is dead; all waves must finish reading it before H overwrites it.
    __syncthreads();

    // epilogue 1: +b1, relu, bf16 -> lds_a (as H). C/D: col=lane&15, row=quad*4+j
#pragma unroll
    for (int ct = 0; ct < 4; ++ct) {
        int c = nbase + ct * 16 + l15;
        float bias = b1[c];
#pragma unroll
        for (int mt = 0; mt < 2; ++mt) {
#pragma unroll
            for (int j = 0; j < 4; ++j) {
                float v = acc[mt][ct][j] + bias;
                v = fmaxf(v, 0.f);
                int r = rbase + mt * 16 + quad * 4 + j;
                unsigned int unit = (unsigned int)(c >> 3) ^ (unsigned int)(r & 31);
                unsigned int addr = (unsigned int)r * 512u + (unit << 4) + (unsigned int)(c & 7) * 2u;
                *reinterpret_cast<unsigned short*>(&lds_a[addr]) = f2bf(v);
            }
        }
    }
    __syncthreads();

    // ================= GEMM2: relu(H @ W2 + b2), fused w3 dot =================
#pragma unroll
    for (int mt = 0; mt < 2; ++mt)
#pragma unroll
        for (int ct = 0; ct < 4; ++ct)
            acc[mt][ct] = (f32x4){0.f, 0.f, 0.f, 0.f};

    LOADB(bb0, wp2, 0)
    LOADB(bb1, wp2, 1)
#pragma unroll
    for (int ks = 0; ks < 8; ++ks) {
        short8 af[2];
        LOADA(af, ks)
        __builtin_amdgcn_s_setprio(1);
        if (ks & 1) { MFMA8(bb1) } else { MFMA8(bb0) }
        __builtin_amdgcn_s_setprio(0);
        if (ks & 1) {
            if (ks + 2 < 8) LOADB(bb1, wp2, ks + 2)
        } else {
            if (ks + 2 < 8) LOADB(bb0, wp2, ks + 2)
        }
    }

    float part[2][4];
#pragma unroll
    for (int mt = 0; mt < 2; ++mt)
#pragma unroll
        for (int j = 0; j < 4; ++j)
            part[mt][j] = 0.f;

#pragma unroll
    for (int ct = 0; ct < 4; ++ct) {
        int c = nbase + ct * 16 + l15;
        float bias = b2[c];
        float w3v  = w3[c];
#pragma unroll
        for (int mt = 0; mt < 2; ++mt)
#pragma unroll
            for (int j = 0; j < 4; ++j) {
                float v = acc[mt][ct][j] + bias;
                v = fmaxf(v, 0.f);
                part[mt][j] += v * w3v;
            }
    }

    // reduce across the 16 lanes of each quad (same rows, different cols)
#pragma unroll
    for (int msk = 8; msk >= 1; msk >>= 1)
#pragma unroll
        for (int mt = 0; mt < 2; ++mt)
#pragma unroll
            for (int j = 0; j < 4; ++j)
                part[mt][j] += __shfl_xor(part[mt][j], msk, 64);

    if (l15 == 0) {
#pragma unroll
        for (int mt = 0; mt < 2; ++mt)
#pragma unroll
            for (int j = 0; j < 4; ++j) {
                int r = rbase + mt * 16 + quad * 4 + j;
                lds_part[nq][r] = part[mt][j];
            }
    }
    __syncthreads();

    if (tid < MT) {
        int gi = base + tid;
        if (gi < M) {
            float s = lds_part[0][tid] + lds_part[1][tid] +
                      lds_part[2][tid] + lds_part[3][tid] + b3[0];
            out[gi] = s;
        }
    }
}

extern "C" void kernel_launch(void* const* d_in, const int* in_sizes, int n_in,
                              void* d_out, int out_size, void* d_ws, size_t ws_size,
                              hipStream_t stream) {
    const int*   pv  = (const int*)d_in[0];
    const int*   qv  = (const int*)d_in[1];
    const float* emb = (const float*)d_in[2];
    const float* w1  = (const float*)d_in[3];
    const float* b1  = (const float*)d_in[4];
    const float* w2  = (const float*)d_in[5];
    const float* b2  = (const float*)d_in[6];
    const float* w3  = (const float*)d_in[7];
    const float* b3  = (const float*)d_in[8];
    float* out = (float*)d_out;
    const int M  = in_sizes[0];
    const int NV = in_sizes[2] / D;

    const size_t tbl_bytes   = (size_t)NV * D * sizeof(unsigned short); // 102.4 MB
    const size_t wpack_bytes = 2u * 65536u * sizeof(unsigned short);    // 256 KB
    const bool use_bf16 = (ws_size >= tbl_bytes + wpack_bytes);         // launch-constant

    unsigned short* table = (unsigned short*)d_ws;
    unsigned short* wpack = use_bf16
        ? (unsigned short*)((char*)d_ws + tbl_bytes)
        : (unsigned short*)d_ws;

    pack_w_kernel<<<32, 512, 0, stream>>>(w1, w2, wpack);

    int nblk = (M + MT - 1) / MT;
    if (use_bf16) {
        int nch = (int)((size_t)NV * D / 8);
        conv_emb_kernel<<<(nch + 255) / 256, 256, 0, stream>>>(emb, table, nch);
        fused_kernel<true><<<nblk, THREADS, 0, stream>>>(
            pv, qv, emb, table, b1, b2, w3, b3, wpack, out, M);
    } else {
        fused_kernel<false><<<nblk, THREADS, 0, stream>>>(
            pv, qv, emb, nullptr, b1, b2, w3, b3, wpack, out, M);
    }
}